// Round 3
// baseline (5903.667 us; speedup 1.0000x reference)
//
#include <hip/hip_runtime.h>
#include <hip/hip_bf16.h>

// ---------------------------------------------------------------------------
// PPO Actor-Critic GNN on MI355X.
// Pipeline: memset ws -> K1 (per-node prep + column reductions)
//           -> K2 (edge aggregation, raw features, f32 atomics)
//           -> K3 (per-node actor MLP, exp(policy), global sums)
//           -> K4 (critic MLP, 1 block) -> K5 (softmax scale).
// Key algebra: critic featc == actor feat[:, [0,1,3]]; normalization commutes
// with segment-mean, so we aggregate RAW columns in K2 and normalize in K3.
// ---------------------------------------------------------------------------

__device__ __forceinline__ float sigf(float x) { return 1.0f / (1.0f + __expf(-x)); }

__device__ __forceinline__ float waveReduceSum(float v) {
#pragma unroll
    for (int off = 32; off > 0; off >>= 1) v += __shfl_down(v, off, 64);
    return v;
}
__device__ __forceinline__ float waveReduceMax(float v) {
#pragma unroll
    for (int off = 32; off > 0; off >>= 1) v = fmaxf(v, __shfl_down(v, off, 64));
    return v;
}

// accum layout (floats):
// [0] max|hop| [1] max|cos| [2] max|rd| [3] max|ett|
// [4] sum ct   [5] sum hop  [6] sum rd
// [7] sum exp(policy)
// [8] sum x_ct (=S_ct/cnt/1440)  [9] sum x_hop_norm  [10] sum x_rd_norm

__global__ void k1_prep(const float* __restrict__ hop, const float* __restrict__ rd,
                        const float* __restrict__ ett, const float* __restrict__ ct,
                        const float* __restrict__ c2n, const float* __restrict__ c2t,
                        float4* __restrict__ featA, float* __restrict__ accum, int n)
{
    int i = blockIdx.x * blockDim.x + threadIdx.x;
    float ah = 0.f, ac = 0.f, ar = 0.f, ae = 0.f, sc = 0.f, sh = 0.f, sr = 0.f;
    if (i < n) {
        float h = hop[i], r = rd[i], e = ett[i], c = ct[i];
        float ax = c2n[3*i+0], ay = c2n[3*i+1], az = c2n[3*i+2];
        float bx = c2t[3*i+0], by = c2t[3*i+1], bz = c2t[3*i+2];
        float dot = ax*bx + ay*by + az*bz;
        float na = fmaxf(sqrtf(ax*ax + ay*ay + az*az), 1e-6f);
        float nb = fmaxf(sqrtf(bx*bx + by*by + bz*bz), 1e-6f);
        float cs = dot / (na * nb);
        featA[i] = make_float4(h, cs, r, e);
        ah = fabsf(h); ac = fabsf(cs); ar = fabsf(r); ae = fabsf(e);
        sc = c; sh = h; sr = r;
    }
    ah = waveReduceMax(ah); ac = waveReduceMax(ac);
    ar = waveReduceMax(ar); ae = waveReduceMax(ae);
    sc = waveReduceSum(sc); sh = waveReduceSum(sh); sr = waveReduceSum(sr);
    if ((threadIdx.x & 63) == 0) {
        // all maxed values are >= 0 so int-ordered atomicMax on the bit pattern works
        atomicMax((int*)(accum + 0), __float_as_int(ah));
        atomicMax((int*)(accum + 1), __float_as_int(ac));
        atomicMax((int*)(accum + 2), __float_as_int(ar));
        atomicMax((int*)(accum + 3), __float_as_int(ae));
        unsafeAtomicAdd(accum + 4, sc);
        unsafeAtomicAdd(accum + 5, sh);
        unsafeAtomicAdd(accum + 6, sr);
    }
}

// S layout: [n][8] floats: 0=ct 1=hop 2=cos 3=rd 4=ett 5=count (6,7 pad)
__global__ void k2_edges(const int* __restrict__ src, const int* __restrict__ dst,
                         const float4* __restrict__ featA, const float* __restrict__ ct,
                         float* __restrict__ S, int E)
{
    int stride = gridDim.x * blockDim.x;
    for (int e = blockIdx.x * blockDim.x + threadIdx.x; e < E; e += stride) {
        int s = src[e], d = dst[e];
        float4 f = featA[s];
        float  c = ct[s];
        float* p = S + (size_t)d * 8;
        unsafeAtomicAdd(p + 0, c);
        unsafeAtomicAdd(p + 1, f.x);
        unsafeAtomicAdd(p + 2, f.y);
        unsafeAtomicAdd(p + 3, f.z);
        unsafeAtomicAdd(p + 4, f.w);
        unsafeAtomicAdd(p + 5, 1.0f);
    }
}

__global__ __launch_bounds__(256) void k3_mlp(
    const float4* __restrict__ featA, const float* __restrict__ ct,
    const float* __restrict__ S, const int* __restrict__ nid,
    const int* __restrict__ currp,
    const float* __restrict__ aW2, const float* __restrict__ ab2,
    const float* __restrict__ aW3, const float* __restrict__ ab3,
    const float* __restrict__ aW4, const float* __restrict__ ab4,
    float* __restrict__ accum, float* __restrict__ out, int n)
{
    int i = blockIdx.x * blockDim.x + threadIdx.x;
    float inv_mh = 1.0f / fmaxf(accum[0], 1e-12f);
    float inv_mc = 1.0f / fmaxf(accum[1], 1e-12f);
    float inv_mr = 1.0f / fmaxf(accum[2], 1e-12f);
    float inv_me = 1.0f / fmaxf(accum[3], 1e-12f);
    int curr = currp[0];
    float ev = 0.f, r0 = 0.f, r1 = 0.f, r3 = 0.f;
    if (i < n) {
        float4 f = featA[i];
        float c = ct[i];
        const float* s = S + (size_t)i * 8;
        float s0 = s[0], s1 = s[1], s2 = s[2], s3 = s[3], s4 = s[4], cnt = s[5];
        float ic = cnt > 0.f ? 1.0f / cnt : 0.f;
        const float k1440 = 1.0f / 1440.0f;
        float x0 = s0 * ic * k1440;
        float x1 = s1 * ic * inv_mh;
        float x2 = s2 * ic * inv_mc;
        float x3 = s3 * ic * inv_mr;
        float x4 = s4 * ic * inv_me;
        float f0 = c * k1440;
        float f1 = f.x * inv_mh, f2 = f.y * inv_mc, f3 = f.z * inv_mr, f4 = f.w * inv_me;
        float g0 = 0.5f*(f0+x0), g1 = 0.5f*(f1+x1), g2 = 0.5f*(f2+x2),
              g3 = 0.5f*(f3+x3), g4 = 0.5f*(f4+x4);

        float acc[64];
#pragma unroll
        for (int k = 0; k < 64; ++k) acc[k] = ab3[k];
        for (int j = 0; j < 128; ++j) {
            float t = ab2[j];
            t = fmaf(g0, aW2[j],       t);
            t = fmaf(g1, aW2[128 + j], t);
            t = fmaf(g2, aW2[256 + j], t);
            t = fmaf(g3, aW2[384 + j], t);
            t = fmaf(g4, aW2[512 + j], t);
            float h = sigf(t);
            const float* w3 = aW3 + j * 64;
#pragma unroll
            for (int k = 0; k < 64; ++k) acc[k] = fmaf(h, w3[k], acc[k]);
        }
        float p = ab4[0];
#pragma unroll
        for (int k = 0; k < 64; ++k) p = fmaf(sigf(acc[k]), aW4[k], p);
        ev = (nid[i] == curr) ? 0.f : __expf(p);
        out[i] = ev;
        r0 = x0; r1 = x1; r3 = x3;
    }
    ev = waveReduceSum(ev); r0 = waveReduceSum(r0);
    r1 = waveReduceSum(r1); r3 = waveReduceSum(r3);
    if ((threadIdx.x & 63) == 0) {
        unsafeAtomicAdd(accum + 7, ev);
        unsafeAtomicAdd(accum + 8, r0);
        unsafeAtomicAdd(accum + 9, r1);
        unsafeAtomicAdd(accum + 10, r3);
    }
}

__global__ void k4_critic(const float* __restrict__ accum,
                          const float* __restrict__ cW2, const float* __restrict__ cb2,
                          const float* __restrict__ cW3, const float* __restrict__ cb3,
                          const float* __restrict__ cW4, const float* __restrict__ cb4,
                          float* __restrict__ out, int n)
{
    __shared__ float v1[128];
    __shared__ float v2[64];
    int t = threadIdx.x;
    float invN = 1.0f / (float)n;
    float inv_mh = 1.0f / fmaxf(accum[0], 1e-12f);
    float inv_mr = 1.0f / fmaxf(accum[2], 1e-12f);
    float cx0 = accum[4] * invN * (1.0f / 1440.0f);
    float cx1 = accum[5] * invN * inv_mh;
    float cx2 = accum[6] * invN * inv_mr;
    float cx3 = accum[8] * invN;
    float cx4 = accum[9] * invN;
    float cx5 = accum[10] * invN;
    if (t < 128) {
        float a = cb2[t];
        a = fmaf(cx0, cW2[t],       a);
        a = fmaf(cx1, cW2[128 + t], a);
        a = fmaf(cx2, cW2[256 + t], a);
        a = fmaf(cx3, cW2[384 + t], a);
        a = fmaf(cx4, cW2[512 + t], a);
        a = fmaf(cx5, cW2[640 + t], a);
        v1[t] = sigf(a);
    }
    __syncthreads();
    if (t < 64) {
        float a = cb3[t];
        for (int j = 0; j < 128; ++j) a = fmaf(v1[j], cW3[j * 64 + t], a);
        v2[t] = sigf(a);
    }
    __syncthreads();
    if (t == 0) {
        float a = cb4[0];
        for (int k = 0; k < 64; ++k) a = fmaf(v2[k], cW4[k], a);
        out[n] = a;  // value
    }
}

__global__ void k5_scale(float* __restrict__ out, const float* __restrict__ accum, int n)
{
    int i = blockIdx.x * blockDim.x + threadIdx.x;
    float inv = 1.0f / accum[7];
    if (i < n) out[i] *= inv;
}

extern "C" void kernel_launch(void* const* d_in, const int* in_sizes, int n_in,
                              void* d_out, int out_size, void* d_ws, size_t ws_size,
                              hipStream_t stream)
{
    const float* hop = (const float*)d_in[0];
    const float* rd  = (const float*)d_in[1];
    const float* ett = (const float*)d_in[2];
    const float* ct  = (const float*)d_in[3];
    const float* c2n = (const float*)d_in[4];
    const float* c2t = (const float*)d_in[5];
    const int*   nid = (const int*)d_in[6];
    const int*   src = (const int*)d_in[7];
    const int*   dst = (const int*)d_in[8];
    const int*   cur = (const int*)d_in[9];
    const float* aW2 = (const float*)d_in[10];
    const float* ab2 = (const float*)d_in[11];
    const float* aW3 = (const float*)d_in[12];
    const float* ab3 = (const float*)d_in[13];
    const float* aW4 = (const float*)d_in[14];
    const float* ab4 = (const float*)d_in[15];
    const float* cW2 = (const float*)d_in[16];
    const float* cb2 = (const float*)d_in[17];
    const float* cW3 = (const float*)d_in[18];
    const float* cb3 = (const float*)d_in[19];
    const float* cW4 = (const float*)d_in[20];
    const float* cb4 = (const float*)d_in[21];

    int n = in_sizes[0];
    int E = in_sizes[7];
    float* out = (float*)d_out;

    char* ws = (char*)d_ws;
    float4* featA = (float4*)ws;                       // 16*n bytes
    float*  S     = (float*)(ws + (size_t)16 * n);     // 32*n bytes
    float*  accum = (float*)(ws + (size_t)48 * n);     // 64 floats

    hipMemsetAsync(S, 0, (size_t)32 * n, stream);
    hipMemsetAsync(accum, 0, 64 * sizeof(float), stream);

    int nb = (n + 255) / 256;
    k1_prep<<<nb, 256, 0, stream>>>(hop, rd, ett, ct, c2n, c2t, featA, accum, n);
    k2_edges<<<4096, 256, 0, stream>>>(src, dst, featA, ct, S, E);
    k3_mlp<<<nb, 256, 0, stream>>>(featA, ct, S, nid, cur,
                                   aW2, ab2, aW3, ab3, aW4, ab4, accum, out, n);
    k4_critic<<<1, 128, 0, stream>>>(accum, cW2, cb2, cW3, cb3, cW4, cb4, out, n);
    k5_scale<<<nb, 256, 0, stream>>>(out, accum, n);
}

// Round 6
// 2531.455 us; speedup vs baseline: 2.3321x; 2.3321x over previous
//
#include <hip/hip_runtime.h>
#include <hip/hip_bf16.h>

// ---------------------------------------------------------------------------
// PPO Actor-Critic GNN on MI355X.
// Round 4: K2 was atomic-count-bound (96M f32 atomics, 3GB HBM writes = 96M x
// 32B sectors, 20G atomics/s). Pack the 6 per-edge sums into 2 u64 fixed-point
// atomics (3 x 21-bit fields, scale 2^12). Quantized pack precomputed in K1.
// Field sums bounded by maxdeg(~65) * 8192 < 2^21 -> no inter-field carry.
// ---------------------------------------------------------------------------

#define M21 ((1u << 21) - 1)
#define QS   4096.0f   // 2^12 fixed-point scale

__device__ __forceinline__ float sigf(float x) { return 1.0f / (1.0f + __expf(-x)); }

__device__ __forceinline__ float waveReduceSum(float v) {
#pragma unroll
    for (int off = 32; off > 0; off >>= 1) v += __shfl_down(v, off, 64);
    return v;
}
__device__ __forceinline__ float waveReduceMax(float v) {
#pragma unroll
    for (int off = 32; off > 0; off >>= 1) v = fmaxf(v, __shfl_down(v, off, 64));
    return v;
}

// accum layout (floats):
// [0] max|hop| [1] max|cos| [2] max|rd| [3] max|ett|
// [4] sum ct   [5] sum hop  [6] sum rd
// [7] sum exp(policy)
// [8] sum x_ct  [9] sum x_hop_norm  [10] sum x_rd_norm

__global__ void k1_prep(const float* __restrict__ hop, const float* __restrict__ rd,
                        const float* __restrict__ ett, const float* __restrict__ ct,
                        const float* __restrict__ c2n, const float* __restrict__ c2t,
                        float4* __restrict__ featA, ulonglong2* __restrict__ packed,
                        float* __restrict__ accum, int n)
{
    int i = blockIdx.x * blockDim.x + threadIdx.x;
    float ah = 0.f, ac = 0.f, ar = 0.f, ae = 0.f, sc = 0.f, sh = 0.f, sr = 0.f;
    if (i < n) {
        float h = hop[i], r = rd[i], e = ett[i], c = ct[i];
        float ax = c2n[3*i+0], ay = c2n[3*i+1], az = c2n[3*i+2];
        float bx = c2t[3*i+0], by = c2t[3*i+1], bz = c2t[3*i+2];
        float dot = ax*bx + ay*by + az*bz;
        float na = fmaxf(sqrtf(ax*ax + ay*ay + az*az), 1e-6f);
        float nb = fmaxf(sqrtf(bx*bx + by*by + bz*bz), 1e-6f);
        float cs = dot / (na * nb);
        featA[i] = make_float4(h, cs, r, e);

        // fixed-point pack for edge aggregation (all fields >= 0, < 2^14)
        unsigned int qc = (unsigned int)rintf(c * (1.0f/1440.0f) * QS);
        unsigned int qh = (unsigned int)rintf(h * QS);
        unsigned int qs = (unsigned int)rintf((cs + 1.0f) * QS);   // cos shifted +1
        unsigned int qr = (unsigned int)rintf(r * QS);
        unsigned int qe = (unsigned int)rintf(e * QS);
        unsigned long long A = (unsigned long long)qc
                             | ((unsigned long long)qh << 21)
                             | ((unsigned long long)qs << 42);
        unsigned long long B = (unsigned long long)qr
                             | ((unsigned long long)qe << 21)
                             | (4096ULL << 42);                    // count increment
        packed[i] = make_ulonglong2(A, B);

        ah = fabsf(h); ac = fabsf(cs); ar = fabsf(r); ae = fabsf(e);
        sc = c; sh = h; sr = r;
    }
    ah = waveReduceMax(ah); ac = waveReduceMax(ac);
    ar = waveReduceMax(ar); ae = waveReduceMax(ae);
    sc = waveReduceSum(sc); sh = waveReduceSum(sh); sr = waveReduceSum(sr);
    if ((threadIdx.x & 63) == 0) {
        atomicMax((int*)(accum + 0), __float_as_int(ah));
        atomicMax((int*)(accum + 1), __float_as_int(ac));
        atomicMax((int*)(accum + 2), __float_as_int(ar));
        atomicMax((int*)(accum + 3), __float_as_int(ae));
        unsafeAtomicAdd(accum + 4, sc);
        unsafeAtomicAdd(accum + 5, sh);
        unsafeAtomicAdd(accum + 6, sr);
    }
}

// S2 layout: [n][2] u64: word0 = {ct, hop, cos+1}, word1 = {rd, ett, count}
__global__ void k2_edges(const int* __restrict__ src, const int* __restrict__ dst,
                         const ulonglong2* __restrict__ packed,
                         unsigned long long* __restrict__ S2, int E)
{
    int stride = gridDim.x * blockDim.x;
    for (int e = blockIdx.x * blockDim.x + threadIdx.x; e < E; e += stride) {
        int s = src[e], d = dst[e];
        ulonglong2 P = packed[s];
        unsigned long long* p = S2 + (size_t)d * 2;
        atomicAdd(p,     P.x);
        atomicAdd(p + 1, P.y);
    }
}

__global__ __launch_bounds__(256) void k3_mlp(
    const float4* __restrict__ featA, const float* __restrict__ ct,
    const ulonglong2* __restrict__ S2, const int* __restrict__ nid,
    const int* __restrict__ currp,
    const float* __restrict__ aW2, const float* __restrict__ ab2,
    const float* __restrict__ aW3, const float* __restrict__ ab3,
    const float* __restrict__ aW4, const float* __restrict__ ab4,
    float* __restrict__ accum, float* __restrict__ out, int n)
{
    int i = blockIdx.x * blockDim.x + threadIdx.x;
    float inv_mh = 1.0f / fmaxf(accum[0], 1e-12f);
    float inv_mc = 1.0f / fmaxf(accum[1], 1e-12f);
    float inv_mr = 1.0f / fmaxf(accum[2], 1e-12f);
    float inv_me = 1.0f / fmaxf(accum[3], 1e-12f);
    int curr = currp[0];
    float ev = 0.f, r0 = 0.f, r1 = 0.f, r3 = 0.f;
    if (i < n) {
        float4 f = featA[i];
        float c = ct[i];
        ulonglong2 P = S2[i];
        unsigned int cnt_fix = (unsigned int)(P.y >> 42);   // 4096 * in-degree
        float ic = cnt_fix ? 1.0f / (float)cnt_fix : 0.f;   // the 2^12 scale cancels
        float x0 = (float)(unsigned int)(P.x         & M21) * ic;            // mean ct/1440
        float x1 = (float)(unsigned int)((P.x >> 21) & M21) * ic * inv_mh;
        float x2 = cnt_fix ? ((float)(unsigned int)(P.x >> 42) * ic - 1.0f) * inv_mc : 0.f;
        float x3 = (float)(unsigned int)(P.y         & M21) * ic * inv_mr;
        float x4 = (float)(unsigned int)((P.y >> 21) & M21) * ic * inv_me;
        float f0 = c * (1.0f/1440.0f);
        float f1 = f.x * inv_mh, f2 = f.y * inv_mc, f3 = f.z * inv_mr, f4 = f.w * inv_me;
        float g0 = 0.5f*(f0+x0), g1 = 0.5f*(f1+x1), g2 = 0.5f*(f2+x2),
              g3 = 0.5f*(f3+x3), g4 = 0.5f*(f4+x4);

        float acc[64];
#pragma unroll
        for (int k = 0; k < 64; ++k) acc[k] = ab3[k];
        for (int j = 0; j < 128; ++j) {
            float t = ab2[j];
            t = fmaf(g0, aW2[j],       t);
            t = fmaf(g1, aW2[128 + j], t);
            t = fmaf(g2, aW2[256 + j], t);
            t = fmaf(g3, aW2[384 + j], t);
            t = fmaf(g4, aW2[512 + j], t);
            float h = sigf(t);
            const float* w3 = aW3 + j * 64;
#pragma unroll
            for (int k = 0; k < 64; ++k) acc[k] = fmaf(h, w3[k], acc[k]);
        }
        float p = ab4[0];
#pragma unroll
        for (int k = 0; k < 64; ++k) p = fmaf(sigf(acc[k]), aW4[k], p);
        ev = (nid[i] == curr) ? 0.f : __expf(p);
        out[i] = ev;
        r0 = x0; r1 = x1; r3 = x3;
    }
    ev = waveReduceSum(ev); r0 = waveReduceSum(r0);
    r1 = waveReduceSum(r1); r3 = waveReduceSum(r3);
    if ((threadIdx.x & 63) == 0) {
        unsafeAtomicAdd(accum + 7, ev);
        unsafeAtomicAdd(accum + 8, r0);
        unsafeAtomicAdd(accum + 9, r1);
        unsafeAtomicAdd(accum + 10, r3);
    }
}

__global__ void k4_critic(const float* __restrict__ accum,
                          const float* __restrict__ cW2, const float* __restrict__ cb2,
                          const float* __restrict__ cW3, const float* __restrict__ cb3,
                          const float* __restrict__ cW4, const float* __restrict__ cb4,
                          float* __restrict__ out, int n)
{
    __shared__ float v1[128];
    __shared__ float v2[64];
    int t = threadIdx.x;
    float invN = 1.0f / (float)n;
    float inv_mh = 1.0f / fmaxf(accum[0], 1e-12f);
    float inv_mr = 1.0f / fmaxf(accum[2], 1e-12f);
    float cx0 = accum[4] * invN * (1.0f / 1440.0f);
    float cx1 = accum[5] * invN * inv_mh;
    float cx2 = accum[6] * invN * inv_mr;
    float cx3 = accum[8] * invN;
    float cx4 = accum[9] * invN;
    float cx5 = accum[10] * invN;
    if (t < 128) {
        float a = cb2[t];
        a = fmaf(cx0, cW2[t],       a);
        a = fmaf(cx1, cW2[128 + t], a);
        a = fmaf(cx2, cW2[256 + t], a);
        a = fmaf(cx3, cW2[384 + t], a);
        a = fmaf(cx4, cW2[512 + t], a);
        a = fmaf(cx5, cW2[640 + t], a);
        v1[t] = sigf(a);
    }
    __syncthreads();
    if (t < 64) {
        float a = cb3[t];
        for (int j = 0; j < 128; ++j) a = fmaf(v1[j], cW3[j * 64 + t], a);
        v2[t] = sigf(a);
    }
    __syncthreads();
    if (t == 0) {
        float a = cb4[0];
        for (int k = 0; k < 64; ++k) a = fmaf(v2[k], cW4[k], a);
        out[n] = a;  // value
    }
}

__global__ void k5_scale(float* __restrict__ out, const float* __restrict__ accum, int n)
{
    int i = blockIdx.x * blockDim.x + threadIdx.x;
    float inv = 1.0f / accum[7];
    if (i < n) out[i] *= inv;
}

extern "C" void kernel_launch(void* const* d_in, const int* in_sizes, int n_in,
                              void* d_out, int out_size, void* d_ws, size_t ws_size,
                              hipStream_t stream)
{
    const float* hop = (const float*)d_in[0];
    const float* rd  = (const float*)d_in[1];
    const float* ett = (const float*)d_in[2];
    const float* ct  = (const float*)d_in[3];
    const float* c2n = (const float*)d_in[4];
    const float* c2t = (const float*)d_in[5];
    const int*   nid = (const int*)d_in[6];
    const int*   src = (const int*)d_in[7];
    const int*   dst = (const int*)d_in[8];
    const int*   cur = (const int*)d_in[9];
    const float* aW2 = (const float*)d_in[10];
    const float* ab2 = (const float*)d_in[11];
    const float* aW3 = (const float*)d_in[12];
    const float* ab3 = (const float*)d_in[13];
    const float* aW4 = (const float*)d_in[14];
    const float* ab4 = (const float*)d_in[15];
    const float* cW2 = (const float*)d_in[16];
    const float* cb2 = (const float*)d_in[17];
    const float* cW3 = (const float*)d_in[18];
    const float* cb3 = (const float*)d_in[19];
    const float* cW4 = (const float*)d_in[20];
    const float* cb4 = (const float*)d_in[21];

    int n = in_sizes[0];
    int E = in_sizes[7];
    float* out = (float*)d_out;

    char* ws = (char*)d_ws;
    float4*     featA  = (float4*)ws;                        // 16*n
    ulonglong2* packed = (ulonglong2*)(ws + (size_t)16 * n); // 16*n
    unsigned long long* S2 = (unsigned long long*)(ws + (size_t)32 * n); // 16*n
    float*      accum  = (float*)(ws + (size_t)48 * n);      // 64 floats

    hipMemsetAsync(S2, 0, (size_t)16 * n, stream);
    hipMemsetAsync(accum, 0, 64 * sizeof(float), stream);

    int nb = (n + 255) / 256;
    k1_prep<<<nb, 256, 0, stream>>>(hop, rd, ett, ct, c2n, c2t, featA, packed, accum, n);
    k2_edges<<<4096, 256, 0, stream>>>(src, dst, packed, S2, E);
    k3_mlp<<<nb, 256, 0, stream>>>(featA, ct, (const ulonglong2*)S2, nid, cur,
                                   aW2, ab2, aW3, ab3, aW4, ab4, accum, out, n);
    k4_critic<<<1, 128, 0, stream>>>(accum, cW2, cb2, cW3, cb3, cW4, cb4, out, n);
    k5_scale<<<nb, 256, 0, stream>>>(out, accum, n);
}

// Round 8
// 1840.697 us; speedup vs baseline: 3.2073x; 1.3753x over previous
//
#include <hip/hip_runtime.h>
#include <hip/hip_bf16.h>

// ---------------------------------------------------------------------------
// PPO Actor-Critic GNN on MI355X.
// Round 7:
//  * K2: 1 u64 atomic/edge (was 2). Fields: ct 11b | hop 11b | cos+1 12b |
//    rd 11b | ett 11b | deg 8b, scale 16. maxdeg~70 -> sums < field caps.
//    K2 is atomic-rate-bound (~22G atomics/s) so cost ~ atomic count.
//  * K3: was ~1130us: MLP inside divergent if(i<n) -> w3 loads not
//    scalarized -> 8192 per-lane VMEM/wave. Now: no divergence (clamped
//    index, masked epilogue), W3 staged in LDS, 4j x 4k register blocking.
// ---------------------------------------------------------------------------

__device__ __forceinline__ float sigf(float x) { return 1.0f / (1.0f + __expf(-x)); }

__device__ __forceinline__ float waveReduceSum(float v) {
#pragma unroll
    for (int off = 32; off > 0; off >>= 1) v += __shfl_down(v, off, 64);
    return v;
}
__device__ __forceinline__ float waveReduceMax(float v) {
#pragma unroll
    for (int off = 32; off > 0; off >>= 1) v = fmaxf(v, __shfl_down(v, off, 64));
    return v;
}

// accum layout (floats):
// [0] max|hop| [1] max|cos| [2] max|rd| [3] max|ett|
// [4] sum ct   [5] sum hop  [6] sum rd
// [7] sum exp(policy)
// [8] sum x_ct  [9] sum x_hop_norm  [10] sum x_rd_norm

__global__ void k1_prep(const float* __restrict__ hop, const float* __restrict__ rd,
                        const float* __restrict__ ett, const float* __restrict__ ct,
                        const float* __restrict__ c2n, const float* __restrict__ c2t,
                        float4* __restrict__ featA, unsigned long long* __restrict__ packed,
                        float* __restrict__ accum, int n)
{
    int i = blockIdx.x * blockDim.x + threadIdx.x;
    float ah = 0.f, ac = 0.f, ar = 0.f, ae = 0.f, sc = 0.f, sh = 0.f, sr = 0.f;
    if (i < n) {
        float h = hop[i], r = rd[i], e = ett[i], c = ct[i];
        float ax = c2n[3*i+0], ay = c2n[3*i+1], az = c2n[3*i+2];
        float bx = c2t[3*i+0], by = c2t[3*i+1], bz = c2t[3*i+2];
        float dot = ax*bx + ay*by + az*bz;
        float na = fmaxf(sqrtf(ax*ax + ay*ay + az*az), 1e-6f);
        float nb = fmaxf(sqrtf(bx*bx + by*by + bz*bz), 1e-6f);
        float cs = dot / (na * nb);
        featA[i] = make_float4(h, cs, r, e);

        // single-u64 fixed-point pack, scale 16
        unsigned long long qc = (unsigned long long)(unsigned int)rintf(c * (16.0f/1440.0f));
        unsigned long long qh = (unsigned long long)(unsigned int)rintf(h * 16.0f);
        unsigned long long qs = (unsigned long long)(unsigned int)rintf((cs + 1.0f) * 16.0f);
        unsigned long long qr = (unsigned long long)(unsigned int)rintf(r * 16.0f);
        unsigned long long qe = (unsigned long long)(unsigned int)rintf(e * 16.0f);
        packed[i] = qc | (qh << 11) | (qs << 22) | (qr << 34) | (qe << 45) | (1ULL << 56);

        ah = fabsf(h); ac = fabsf(cs); ar = fabsf(r); ae = fabsf(e);
        sc = c; sh = h; sr = r;
    }
    ah = waveReduceMax(ah); ac = waveReduceMax(ac);
    ar = waveReduceMax(ar); ae = waveReduceMax(ae);
    sc = waveReduceSum(sc); sh = waveReduceSum(sh); sr = waveReduceSum(sr);
    if ((threadIdx.x & 63) == 0) {
        atomicMax((int*)(accum + 0), __float_as_int(ah));
        atomicMax((int*)(accum + 1), __float_as_int(ac));
        atomicMax((int*)(accum + 2), __float_as_int(ar));
        atomicMax((int*)(accum + 3), __float_as_int(ae));
        unsafeAtomicAdd(accum + 4, sc);
        unsafeAtomicAdd(accum + 5, sh);
        unsafeAtomicAdd(accum + 6, sr);
    }
}

__global__ void k2_edges(const int* __restrict__ src, const int* __restrict__ dst,
                         const unsigned long long* __restrict__ packed,
                         unsigned long long* __restrict__ S2, int E)
{
    int stride = gridDim.x * blockDim.x;
    for (int e = blockIdx.x * blockDim.x + threadIdx.x; e < E; e += stride) {
        int s = src[e], d = dst[e];
        atomicAdd(S2 + d, packed[s]);
    }
}

__global__ __launch_bounds__(256) void k3_mlp(
    const float4* __restrict__ featA, const float* __restrict__ ct,
    const unsigned long long* __restrict__ S2, const int* __restrict__ nid,
    const int* __restrict__ currp,
    const float* __restrict__ aW2, const float* __restrict__ ab2,
    const float* __restrict__ aW3, const float* __restrict__ ab3,
    const float* __restrict__ aW4, const float* __restrict__ ab4,
    float* __restrict__ accum, float* __restrict__ out, int n)
{
    __shared__ float w3s[128 * 64];   // 32 KB
    for (int idx = threadIdx.x; idx < 128 * 64; idx += 256)
        w3s[idx] = aW3[idx];
    __syncthreads();

    int i0 = blockIdx.x * blockDim.x + threadIdx.x;
    int i = i0 < n ? i0 : n - 1;           // clamp: no divergence in compute
    bool valid = i0 < n;

    float inv_mh = 1.0f / fmaxf(accum[0], 1e-12f);
    float inv_mc = 1.0f / fmaxf(accum[1], 1e-12f);
    float inv_mr = 1.0f / fmaxf(accum[2], 1e-12f);
    float inv_me = 1.0f / fmaxf(accum[3], 1e-12f);
    int curr = currp[0];

    float4 f = featA[i];
    float c = ct[i];
    unsigned long long P = S2[i];
    unsigned int qct = (unsigned int)(P         & 0x7FFULL);
    unsigned int qh  = (unsigned int)((P >> 11) & 0x7FFULL);
    unsigned int qcs = (unsigned int)((P >> 22) & 0xFFFULL);
    unsigned int qr  = (unsigned int)((P >> 34) & 0x7FFULL);
    unsigned int qe  = (unsigned int)((P >> 45) & 0x7FFULL);
    unsigned int deg = (unsigned int)(P >> 56);
    float icd = deg ? 1.0f / (16.0f * (float)deg) : 0.f;
    float x0 = (float)qct * icd;                                   // mean ct/1440
    float x1 = (float)qh  * icd * inv_mh;
    float x2 = deg ? ((float)qcs * icd - 1.0f) * inv_mc : 0.f;
    float x3 = (float)qr  * icd * inv_mr;
    float x4 = (float)qe  * icd * inv_me;
    float f0 = c * (1.0f/1440.0f);
    float f1 = f.x * inv_mh, f2 = f.y * inv_mc, f3 = f.z * inv_mr, f4 = f.w * inv_me;
    float g0 = 0.5f*(f0+x0), g1 = 0.5f*(f1+x1), g2 = 0.5f*(f2+x2),
          g3 = 0.5f*(f3+x3), g4 = 0.5f*(f4+x4);

    float acc[64];
#pragma unroll
    for (int k = 0; k < 64; ++k) acc[k] = ab3[k];

    for (int j = 0; j < 128; j += 4) {
        float hv[4];
#pragma unroll
        for (int jj = 0; jj < 4; ++jj) {
            float t = ab2[j + jj];
            t = fmaf(g0, aW2[j + jj],       t);
            t = fmaf(g1, aW2[128 + j + jj], t);
            t = fmaf(g2, aW2[256 + j + jj], t);
            t = fmaf(g3, aW2[384 + j + jj], t);
            t = fmaf(g4, aW2[512 + j + jj], t);
            hv[jj] = sigf(t);
        }
        const float4* r0 = (const float4*)&w3s[(j + 0) * 64];
        const float4* r1 = (const float4*)&w3s[(j + 1) * 64];
        const float4* r2 = (const float4*)&w3s[(j + 2) * 64];
        const float4* r3 = (const float4*)&w3s[(j + 3) * 64];
#pragma unroll
        for (int k4 = 0; k4 < 16; ++k4) {
            float4 a = r0[k4], b = r1[k4], cc = r2[k4], d = r3[k4];
            acc[4*k4+0] = fmaf(hv[0], a.x, fmaf(hv[1], b.x, fmaf(hv[2], cc.x, fmaf(hv[3], d.x, acc[4*k4+0]))));
            acc[4*k4+1] = fmaf(hv[0], a.y, fmaf(hv[1], b.y, fmaf(hv[2], cc.y, fmaf(hv[3], d.y, acc[4*k4+1]))));
            acc[4*k4+2] = fmaf(hv[0], a.z, fmaf(hv[1], b.z, fmaf(hv[2], cc.z, fmaf(hv[3], d.z, acc[4*k4+2]))));
            acc[4*k4+3] = fmaf(hv[0], a.w, fmaf(hv[1], b.w, fmaf(hv[2], cc.w, fmaf(hv[3], d.w, acc[4*k4+3]))));
        }
    }

    float p = ab4[0];
#pragma unroll
    for (int k = 0; k < 64; ++k) p = fmaf(sigf(acc[k]), aW4[k], p);

    float ev = (valid && nid[i] != curr) ? __expf(p) : 0.f;
    if (valid) out[i0] = ev;
    float r0s = valid ? x0 : 0.f;
    float r1s = valid ? x1 : 0.f;
    float r3s = valid ? x3 : 0.f;

    ev  = waveReduceSum(ev);
    r0s = waveReduceSum(r0s);
    r1s = waveReduceSum(r1s);
    r3s = waveReduceSum(r3s);
    if ((threadIdx.x & 63) == 0) {
        unsafeAtomicAdd(accum + 7, ev);
        unsafeAtomicAdd(accum + 8, r0s);
        unsafeAtomicAdd(accum + 9, r1s);
        unsafeAtomicAdd(accum + 10, r3s);
    }
}

__global__ void k4_critic(const float* __restrict__ accum,
                          const float* __restrict__ cW2, const float* __restrict__ cb2,
                          const float* __restrict__ cW3, const float* __restrict__ cb3,
                          const float* __restrict__ cW4, const float* __restrict__ cb4,
                          float* __restrict__ out, int n)
{
    __shared__ float v1[128];
    __shared__ float v2[64];
    int t = threadIdx.x;
    float invN = 1.0f / (float)n;
    float inv_mh = 1.0f / fmaxf(accum[0], 1e-12f);
    float inv_mr = 1.0f / fmaxf(accum[2], 1e-12f);
    float cx0 = accum[4] * invN * (1.0f / 1440.0f);
    float cx1 = accum[5] * invN * inv_mh;
    float cx2 = accum[6] * invN * inv_mr;
    float cx3 = accum[8] * invN;
    float cx4 = accum[9] * invN;
    float cx5 = accum[10] * invN;
    if (t < 128) {
        float a = cb2[t];
        a = fmaf(cx0, cW2[t],       a);
        a = fmaf(cx1, cW2[128 + t], a);
        a = fmaf(cx2, cW2[256 + t], a);
        a = fmaf(cx3, cW2[384 + t], a);
        a = fmaf(cx4, cW2[512 + t], a);
        a = fmaf(cx5, cW2[640 + t], a);
        v1[t] = sigf(a);
    }
    __syncthreads();
    if (t < 64) {
        float a = cb3[t];
        for (int j = 0; j < 128; ++j) a = fmaf(v1[j], cW3[j * 64 + t], a);
        v2[t] = sigf(a);
    }
    __syncthreads();
    if (t == 0) {
        float a = cb4[0];
        for (int k = 0; k < 64; ++k) a = fmaf(v2[k], cW4[k], a);
        out[n] = a;  // value
    }
}

__global__ void k5_scale(float* __restrict__ out, const float* __restrict__ accum, int n)
{
    int i = blockIdx.x * blockDim.x + threadIdx.x;
    float inv = 1.0f / accum[7];
    if (i < n) out[i] *= inv;
}

extern "C" void kernel_launch(void* const* d_in, const int* in_sizes, int n_in,
                              void* d_out, int out_size, void* d_ws, size_t ws_size,
                              hipStream_t stream)
{
    const float* hop = (const float*)d_in[0];
    const float* rd  = (const float*)d_in[1];
    const float* ett = (const float*)d_in[2];
    const float* ct  = (const float*)d_in[3];
    const float* c2n = (const float*)d_in[4];
    const float* c2t = (const float*)d_in[5];
    const int*   nid = (const int*)d_in[6];
    const int*   src = (const int*)d_in[7];
    const int*   dst = (const int*)d_in[8];
    const int*   cur = (const int*)d_in[9];
    const float* aW2 = (const float*)d_in[10];
    const float* ab2 = (const float*)d_in[11];
    const float* aW3 = (const float*)d_in[12];
    const float* ab3 = (const float*)d_in[13];
    const float* aW4 = (const float*)d_in[14];
    const float* ab4 = (const float*)d_in[15];
    const float* cW2 = (const float*)d_in[16];
    const float* cb2 = (const float*)d_in[17];
    const float* cW3 = (const float*)d_in[18];
    const float* cb3 = (const float*)d_in[19];
    const float* cW4 = (const float*)d_in[20];
    const float* cb4 = (const float*)d_in[21];

    int n = in_sizes[0];
    int E = in_sizes[7];
    float* out = (float*)d_out;

    char* ws = (char*)d_ws;
    float4*             featA  = (float4*)ws;                                 // 16*n
    unsigned long long* packed = (unsigned long long*)(ws + (size_t)16 * n);  // 8*n
    unsigned long long* S2     = (unsigned long long*)(ws + (size_t)24 * n);  // 8*n
    float*              accum  = (float*)(ws + (size_t)32 * n);               // 64 floats

    hipMemsetAsync(S2, 0, (size_t)8 * n, stream);
    hipMemsetAsync(accum, 0, 64 * sizeof(float), stream);

    int nb = (n + 255) / 256;
    k1_prep<<<nb, 256, 0, stream>>>(hop, rd, ett, ct, c2n, c2t, featA, packed, accum, n);
    k2_edges<<<4096, 256, 0, stream>>>(src, dst, packed, S2, E);
    k3_mlp<<<nb, 256, 0, stream>>>(featA, ct, S2, nid, cur,
                                   aW2, ab2, aW3, ab3, aW4, ab4, accum, out, n);
    k4_critic<<<1, 128, 0, stream>>>(accum, cW2, cb2, cW3, cb3, cW4, cb4, out, n);
    k5_scale<<<nb, 256, 0, stream>>>(out, accum, n);
}

// Round 9
// 1412.470 us; speedup vs baseline: 4.1797x; 1.3032x over previous
//
#include <hip/hip_runtime.h>
#include <hip/hip_bf16.h>

// ---------------------------------------------------------------------------
// PPO Actor-Critic GNN on MI355X.
// Round 9: K2 was atomic-rate-bound (~23G device-scope atomics/s; each atomic
// = 32B memory-side sector RMW because cross-XCD coherence point is memory
// side). Replace 16M global atomics with two-phase bucketing:
//   k2a: histogram+scatter edges into 123 dst-buckets (4096 nodes each) as
//        u32 records {src:20|dstLocal:12}; per-block LDS histogram -> only
//        123 global atomics per block.
//   k2b: per bucket x 4 slices, accumulate packed u64 in 32KB LDS via LDS
//        atomics (~1/cyc/CU), flush non-atomically to 4 replica arrays.
//   k3 sums the 4 replicas (integer adds -> bit-deterministic).
// Fallback to round-8 single-atomic path if ws too small or nb > 128.
// ---------------------------------------------------------------------------

typedef unsigned int u32;
typedef unsigned long long u64;

__device__ __forceinline__ float sigf(float x) { return 1.0f / (1.0f + __expf(-x)); }

__device__ __forceinline__ float waveReduceSum(float v) {
#pragma unroll
    for (int off = 32; off > 0; off >>= 1) v += __shfl_down(v, off, 64);
    return v;
}
__device__ __forceinline__ float waveReduceMax(float v) {
#pragma unroll
    for (int off = 32; off > 0; off >>= 1) v = fmaxf(v, __shfl_down(v, off, 64));
    return v;
}

// accum layout (floats):
// [0] max|hop| [1] max|cos| [2] max|rd| [3] max|ett|
// [4] sum ct   [5] sum hop  [6] sum rd
// [7] sum exp(policy)
// [8] sum x_ct  [9] sum x_hop_norm  [10] sum x_rd_norm

__global__ void k1_prep(const float* __restrict__ hop, const float* __restrict__ rd,
                        const float* __restrict__ ett, const float* __restrict__ ct,
                        const float* __restrict__ c2n, const float* __restrict__ c2t,
                        float4* __restrict__ featA, u64* __restrict__ packed,
                        float* __restrict__ accum, int n)
{
    int i = blockIdx.x * blockDim.x + threadIdx.x;
    float ah = 0.f, ac = 0.f, ar = 0.f, ae = 0.f, sc = 0.f, sh = 0.f, sr = 0.f;
    if (i < n) {
        float h = hop[i], r = rd[i], e = ett[i], c = ct[i];
        float ax = c2n[3*i+0], ay = c2n[3*i+1], az = c2n[3*i+2];
        float bx = c2t[3*i+0], by = c2t[3*i+1], bz = c2t[3*i+2];
        float dot = ax*bx + ay*by + az*bz;
        float na = fmaxf(sqrtf(ax*ax + ay*ay + az*az), 1e-6f);
        float nb = fmaxf(sqrtf(bx*bx + by*by + bz*bz), 1e-6f);
        float cs = dot / (na * nb);
        featA[i] = make_float4(h, cs, r, e);

        // single-u64 fixed-point pack, scale 16
        // fields: ct 11b | hop 11b | cos+1 12b | rd 11b | ett 11b | deg 8b
        u64 qc = (u64)(u32)rintf(c * (16.0f/1440.0f));
        u64 qh = (u64)(u32)rintf(h * 16.0f);
        u64 qs = (u64)(u32)rintf((cs + 1.0f) * 16.0f);
        u64 qr = (u64)(u32)rintf(r * 16.0f);
        u64 qe = (u64)(u32)rintf(e * 16.0f);
        packed[i] = qc | (qh << 11) | (qs << 22) | (qr << 34) | (qe << 45) | (1ULL << 56);

        ah = fabsf(h); ac = fabsf(cs); ar = fabsf(r); ae = fabsf(e);
        sc = c; sh = h; sr = r;
    }
    ah = waveReduceMax(ah); ac = waveReduceMax(ac);
    ar = waveReduceMax(ar); ae = waveReduceMax(ae);
    sc = waveReduceSum(sc); sh = waveReduceSum(sh); sr = waveReduceSum(sr);
    if ((threadIdx.x & 63) == 0) {
        atomicMax((int*)(accum + 0), __float_as_int(ah));
        atomicMax((int*)(accum + 1), __float_as_int(ac));
        atomicMax((int*)(accum + 2), __float_as_int(ar));
        atomicMax((int*)(accum + 3), __float_as_int(ae));
        unsafeAtomicAdd(accum + 4, sc);
        unsafeAtomicAdd(accum + 5, sh);
        unsafeAtomicAdd(accum + 6, sr);
    }
}

// ---- fallback path (round-8): one u64 atomic per edge --------------------
__global__ void k2_atomic(const int* __restrict__ src, const int* __restrict__ dst,
                          const u64* __restrict__ packed, u64* __restrict__ S2, int E)
{
    int stride = gridDim.x * blockDim.x;
    for (int e = blockIdx.x * blockDim.x + threadIdx.x; e < E; e += stride) {
        atomicAdd(S2 + dst[e], packed[src[e]]);
    }
}

// ---- Phase A: bucket-scatter ---------------------------------------------
// records[b*cap + slot] = (src << 12) | (dst & 4095),  bucket b = dst >> 12
__global__ __launch_bounds__(256) void k2a_scatter(
    const int* __restrict__ src, const int* __restrict__ dst,
    u32* __restrict__ records, u32* __restrict__ bucketPos,
    int E, int nb, int cap, int chunk)
{
    __shared__ u32 hist[128];
    __shared__ u32 base[128];
    int b0 = blockIdx.x * chunk;
    int b1 = min(b0 + chunk, E);
    for (int i = threadIdx.x; i < nb; i += 256) hist[i] = 0;
    __syncthreads();
    for (int e = b0 + threadIdx.x; e < b1; e += 256)
        atomicAdd(&hist[dst[e] >> 12], 1u);
    __syncthreads();
    for (int i = threadIdx.x; i < nb; i += 256) {
        base[i] = atomicAdd(&bucketPos[i], hist[i]);
        hist[i] = 0;
    }
    __syncthreads();
    for (int e = b0 + threadIdx.x; e < b1; e += 256) {
        int d = dst[e];
        int b = d >> 12;
        u32 off = base[b] + atomicAdd(&hist[b], 1u);
        if (off < (u32)cap)
            records[(size_t)b * cap + off] = ((u32)src[e] << 12) | (u32)(d & 4095);
    }
}

// ---- Phase B: LDS accumulate + replica flush -----------------------------
__global__ __launch_bounds__(256) void k2b_accum(
    const u32* __restrict__ records, const u32* __restrict__ bucketPos,
    const u64* __restrict__ packed, u64* __restrict__ S2rep,
    int n, int cap, int nsl)
{
    __shared__ u64 acc[4096];   // 32 KB
    int bucket = blockIdx.x / nsl;
    int slice  = blockIdx.x % nsl;
    int nodeBase = bucket << 12;
    int nNodes = min(4096, n - nodeBase);
    for (int i = threadIdx.x; i < 4096; i += 256) acc[i] = 0;
    __syncthreads();
    u32 cnt = bucketPos[bucket];
    if (cnt > (u32)cap) cnt = (u32)cap;
    u32 lo = (u32)(((u64)cnt * (u32)slice) / (u32)nsl);
    u32 hi = (u32)(((u64)cnt * (u32)(slice + 1)) / (u32)nsl);
    const u32* rec = records + (size_t)bucket * cap;
    for (u32 r = lo + threadIdx.x; r < hi; r += 256) {
        u32 v = rec[r];
        atomicAdd(&acc[v & 4095u], packed[v >> 12]);
    }
    __syncthreads();
    u64* dstp = S2rep + (size_t)slice * n + nodeBase;
    for (int i = threadIdx.x; i < nNodes; i += 256) dstp[i] = acc[i];
}

__global__ __launch_bounds__(256) void k3_mlp(
    const float4* __restrict__ featA, const float* __restrict__ ct,
    const u64* __restrict__ S2rep, int nsl, const int* __restrict__ nid,
    const int* __restrict__ currp,
    const float* __restrict__ aW2, const float* __restrict__ ab2,
    const float* __restrict__ aW3, const float* __restrict__ ab3,
    const float* __restrict__ aW4, const float* __restrict__ ab4,
    float* __restrict__ accum, float* __restrict__ out, int n)
{
    __shared__ float w3s[128 * 64];   // 32 KB
    for (int idx = threadIdx.x; idx < 128 * 64; idx += 256)
        w3s[idx] = aW3[idx];
    __syncthreads();

    int i0 = blockIdx.x * blockDim.x + threadIdx.x;
    int i = i0 < n ? i0 : n - 1;           // clamp: no divergence in compute
    bool valid = i0 < n;

    float inv_mh = 1.0f / fmaxf(accum[0], 1e-12f);
    float inv_mc = 1.0f / fmaxf(accum[1], 1e-12f);
    float inv_mr = 1.0f / fmaxf(accum[2], 1e-12f);
    float inv_me = 1.0f / fmaxf(accum[3], 1e-12f);
    int curr = currp[0];

    float4 f = featA[i];
    float c = ct[i];
    u64 P = 0;
    for (int s = 0; s < nsl; ++s) P += S2rep[(size_t)s * n + i];
    u32 qct = (u32)(P         & 0x7FFULL);
    u32 qh  = (u32)((P >> 11) & 0x7FFULL);
    u32 qcs = (u32)((P >> 22) & 0xFFFULL);
    u32 qr  = (u32)((P >> 34) & 0x7FFULL);
    u32 qe  = (u32)((P >> 45) & 0x7FFULL);
    u32 deg = (u32)(P >> 56);
    float icd = deg ? 1.0f / (16.0f * (float)deg) : 0.f;
    float x0 = (float)qct * icd;                                   // mean ct/1440
    float x1 = (float)qh  * icd * inv_mh;
    float x2 = deg ? ((float)qcs * icd - 1.0f) * inv_mc : 0.f;
    float x3 = (float)qr  * icd * inv_mr;
    float x4 = (float)qe  * icd * inv_me;
    float f0 = c * (1.0f/1440.0f);
    float f1 = f.x * inv_mh, f2 = f.y * inv_mc, f3 = f.z * inv_mr, f4 = f.w * inv_me;
    float g0 = 0.5f*(f0+x0), g1 = 0.5f*(f1+x1), g2 = 0.5f*(f2+x2),
          g3 = 0.5f*(f3+x3), g4 = 0.5f*(f4+x4);

    float acc[64];
#pragma unroll
    for (int k = 0; k < 64; ++k) acc[k] = ab3[k];

    for (int j = 0; j < 128; j += 4) {
        float hv[4];
#pragma unroll
        for (int jj = 0; jj < 4; ++jj) {
            float t = ab2[j + jj];
            t = fmaf(g0, aW2[j + jj],       t);
            t = fmaf(g1, aW2[128 + j + jj], t);
            t = fmaf(g2, aW2[256 + j + jj], t);
            t = fmaf(g3, aW2[384 + j + jj], t);
            t = fmaf(g4, aW2[512 + j + jj], t);
            hv[jj] = sigf(t);
        }
        const float4* r0 = (const float4*)&w3s[(j + 0) * 64];
        const float4* r1 = (const float4*)&w3s[(j + 1) * 64];
        const float4* r2 = (const float4*)&w3s[(j + 2) * 64];
        const float4* r3 = (const float4*)&w3s[(j + 3) * 64];
#pragma unroll
        for (int k4 = 0; k4 < 16; ++k4) {
            float4 a = r0[k4], b = r1[k4], cc = r2[k4], d = r3[k4];
            acc[4*k4+0] = fmaf(hv[0], a.x, fmaf(hv[1], b.x, fmaf(hv[2], cc.x, fmaf(hv[3], d.x, acc[4*k4+0]))));
            acc[4*k4+1] = fmaf(hv[0], a.y, fmaf(hv[1], b.y, fmaf(hv[2], cc.y, fmaf(hv[3], d.y, acc[4*k4+1]))));
            acc[4*k4+2] = fmaf(hv[0], a.z, fmaf(hv[1], b.z, fmaf(hv[2], cc.z, fmaf(hv[3], d.z, acc[4*k4+2]))));
            acc[4*k4+3] = fmaf(hv[0], a.w, fmaf(hv[1], b.w, fmaf(hv[2], cc.w, fmaf(hv[3], d.w, acc[4*k4+3]))));
        }
    }

    float p = ab4[0];
#pragma unroll
    for (int k = 0; k < 64; ++k) p = fmaf(sigf(acc[k]), aW4[k], p);

    float ev = (valid && nid[i] != curr) ? __expf(p) : 0.f;
    if (valid) out[i0] = ev;
    float r0s = valid ? x0 : 0.f;
    float r1s = valid ? x1 : 0.f;
    float r3s = valid ? x3 : 0.f;

    ev  = waveReduceSum(ev);
    r0s = waveReduceSum(r0s);
    r1s = waveReduceSum(r1s);
    r3s = waveReduceSum(r3s);
    if ((threadIdx.x & 63) == 0) {
        unsafeAtomicAdd(accum + 7, ev);
        unsafeAtomicAdd(accum + 8, r0s);
        unsafeAtomicAdd(accum + 9, r1s);
        unsafeAtomicAdd(accum + 10, r3s);
    }
}

__global__ void k4_critic(const float* __restrict__ accum,
                          const float* __restrict__ cW2, const float* __restrict__ cb2,
                          const float* __restrict__ cW3, const float* __restrict__ cb3,
                          const float* __restrict__ cW4, const float* __restrict__ cb4,
                          float* __restrict__ out, int n)
{
    __shared__ float v1[128];
    __shared__ float v2[64];
    int t = threadIdx.x;
    float invN = 1.0f / (float)n;
    float inv_mh = 1.0f / fmaxf(accum[0], 1e-12f);
    float inv_mr = 1.0f / fmaxf(accum[2], 1e-12f);
    float cx0 = accum[4] * invN * (1.0f / 1440.0f);
    float cx1 = accum[5] * invN * inv_mh;
    float cx2 = accum[6] * invN * inv_mr;
    float cx3 = accum[8] * invN;
    float cx4 = accum[9] * invN;
    float cx5 = accum[10] * invN;
    if (t < 128) {
        float a = cb2[t];
        a = fmaf(cx0, cW2[t],       a);
        a = fmaf(cx1, cW2[128 + t], a);
        a = fmaf(cx2, cW2[256 + t], a);
        a = fmaf(cx3, cW2[384 + t], a);
        a = fmaf(cx4, cW2[512 + t], a);
        a = fmaf(cx5, cW2[640 + t], a);
        v1[t] = sigf(a);
    }
    __syncthreads();
    if (t < 64) {
        float a = cb3[t];
        for (int j = 0; j < 128; ++j) a = fmaf(v1[j], cW3[j * 64 + t], a);
        v2[t] = sigf(a);
    }
    __syncthreads();
    if (t == 0) {
        float a = cb4[0];
        for (int k = 0; k < 64; ++k) a = fmaf(v2[k], cW4[k], a);
        out[n] = a;  // value
    }
}

__global__ void k5_scale(float* __restrict__ out, const float* __restrict__ accum, int n)
{
    int i = blockIdx.x * blockDim.x + threadIdx.x;
    float inv = 1.0f / accum[7];
    if (i < n) out[i] *= inv;
}

extern "C" void kernel_launch(void* const* d_in, const int* in_sizes, int n_in,
                              void* d_out, int out_size, void* d_ws, size_t ws_size,
                              hipStream_t stream)
{
    const float* hop = (const float*)d_in[0];
    const float* rd  = (const float*)d_in[1];
    const float* ett = (const float*)d_in[2];
    const float* ct  = (const float*)d_in[3];
    const float* c2n = (const float*)d_in[4];
    const float* c2t = (const float*)d_in[5];
    const int*   nid = (const int*)d_in[6];
    const int*   src = (const int*)d_in[7];
    const int*   dst = (const int*)d_in[8];
    const int*   cur = (const int*)d_in[9];
    const float* aW2 = (const float*)d_in[10];
    const float* ab2 = (const float*)d_in[11];
    const float* aW3 = (const float*)d_in[12];
    const float* ab3 = (const float*)d_in[13];
    const float* aW4 = (const float*)d_in[14];
    const float* ab4 = (const float*)d_in[15];
    const float* cW2 = (const float*)d_in[16];
    const float* cb2 = (const float*)d_in[17];
    const float* cW3 = (const float*)d_in[18];
    const float* cb3 = (const float*)d_in[19];
    const float* cW4 = (const float*)d_in[20];
    const float* cb4 = (const float*)d_in[21];

    int n = in_sizes[0];
    int E = in_sizes[7];
    float* out = (float*)d_out;

    const int NSL = 4;
    int nb  = (n + 4095) >> 12;                       // buckets of 4096 nodes
    int cap = E / (nb > 0 ? nb : 1) + 8192;           // >25 sigma slack

    char* ws = (char*)d_ws;
    float4* featA  = (float4*)ws;                     // 16n
    u64*    packed = (u64*)(ws + (size_t)16 * n);     // 8n
    u64*    S2rep  = (u64*)(ws + (size_t)24 * n);     // 8n * NSL = 32n
    float*  accum  = (float*)(ws + (size_t)56 * n);   // 256 B
    u32*    bucketPos = (u32*)(ws + (size_t)56 * n + 256);
    u32*    records   = (u32*)(ws + (size_t)56 * n + 4096);
    size_t needed = (size_t)56 * n + 4096 + (size_t)nb * cap * 4;

    int nbk = (n + 255) / 256;
    bool bucketPath = (ws_size >= needed) && (nb <= 128);

    if (bucketPath) {
        // zero accum + bucketPos (contiguous 4 KB)
        hipMemsetAsync(accum, 0, 4096, stream);
        k1_prep<<<nbk, 256, 0, stream>>>(hop, rd, ett, ct, c2n, c2t, featA, packed, accum, n);
        int chunk = (E + 1023) / 1024;
        k2a_scatter<<<1024, 256, 0, stream>>>(src, dst, records, bucketPos, E, nb, cap, chunk);
        k2b_accum<<<nb * NSL, 256, 0, stream>>>(records, bucketPos, packed, S2rep, n, cap, NSL);
        k3_mlp<<<nbk, 256, 0, stream>>>(featA, ct, S2rep, NSL, nid, cur,
                                        aW2, ab2, aW3, ab3, aW4, ab4, accum, out, n);
    } else {
        // fallback: round-8 layout, 1 global u64 atomic per edge
        u64*   S2f    = (u64*)(ws + (size_t)24 * n);
        float* accumF = (float*)(ws + (size_t)32 * n);
        accum = accumF;
        hipMemsetAsync(S2f, 0, (size_t)8 * n, stream);
        hipMemsetAsync(accumF, 0, 256, stream);
        k1_prep<<<nbk, 256, 0, stream>>>(hop, rd, ett, ct, c2n, c2t, featA, packed, accumF, n);
        k2_atomic<<<4096, 256, 0, stream>>>(src, dst, packed, S2f, E);
        k3_mlp<<<nbk, 256, 0, stream>>>(featA, ct, S2f, 1, nid, cur,
                                        aW2, ab2, aW3, ab3, aW4, ab4, accumF, out, n);
    }
    k4_critic<<<1, 128, 0, stream>>>(accum, cW2, cb2, cW3, cb3, cW4, cb4, out, n);
    k5_scale<<<nbk, 256, 0, stream>>>(out, accum, n);
}

// Round 10
// 467.870 us; speedup vs baseline: 12.6182x; 3.0189x over previous
//
#include <hip/hip_runtime.h>
#include <hip/hip_bf16.h>

// ---------------------------------------------------------------------------
// PPO Actor-Critic GNN on MI355X.
// Round 10: rounds 3-9 hid a constant ~1.1ms: same-cache-line atomic tails.
// k1 fired 7816 waves x 7 atomics at ONE 64B line (~55K serialized memory-
// side RMWs ~ 650us); k3 fired 4/wave (~400us). Replace ALL global-atomic
// reductions with: per-block LDS reduce -> non-atomic partials[bid] write ->
// single-block k1b/k3b final reduce (deterministic).
// K2 stays two-phase bucketed (round 9): scatter into 123 dst-buckets, then
// LDS u64 accumulate per bucket, 4 slice-replicas summed in k3.
// ---------------------------------------------------------------------------

typedef unsigned int u32;
typedef unsigned long long u64;

__device__ __forceinline__ float sigf(float x) { return 1.0f / (1.0f + __expf(-x)); }

__device__ __forceinline__ float waveReduceSum(float v) {
#pragma unroll
    for (int off = 32; off > 0; off >>= 1) v += __shfl_down(v, off, 64);
    return v;
}
__device__ __forceinline__ float waveReduceMax(float v) {
#pragma unroll
    for (int off = 32; off > 0; off >>= 1) v = fmaxf(v, __shfl_down(v, off, 64));
    return v;
}

// accum layout (floats):
// [0] max|hop| [1] max|cos| [2] max|rd| [3] max|ett|
// [4] sum ct   [5] sum hop  [6] sum rd
// [7] sum exp(policy)
// [8] sum x_ct  [9] sum x_hop_norm  [10] sum x_rd_norm

__global__ __launch_bounds__(256) void k1_prep(
    const float* __restrict__ hop, const float* __restrict__ rd,
    const float* __restrict__ ett, const float* __restrict__ ct,
    const float* __restrict__ c2n, const float* __restrict__ c2t,
    float4* __restrict__ featA, u64* __restrict__ packed,
    float* __restrict__ partials, int n)
{
    int i = blockIdx.x * blockDim.x + threadIdx.x;
    float ah = 0.f, ac = 0.f, ar = 0.f, ae = 0.f, sc = 0.f, sh = 0.f, sr = 0.f;
    if (i < n) {
        float h = hop[i], r = rd[i], e = ett[i], c = ct[i];
        float ax = c2n[3*i+0], ay = c2n[3*i+1], az = c2n[3*i+2];
        float bx = c2t[3*i+0], by = c2t[3*i+1], bz = c2t[3*i+2];
        float dot = ax*bx + ay*by + az*bz;
        float na = fmaxf(sqrtf(ax*ax + ay*ay + az*az), 1e-6f);
        float nb = fmaxf(sqrtf(bx*bx + by*by + bz*bz), 1e-6f);
        float cs = dot / (na * nb);
        featA[i] = make_float4(h, cs, r, e);

        // single-u64 fixed-point pack, scale 16
        // fields: ct 11b | hop 11b | cos+1 12b | rd 11b | ett 11b | deg 8b
        u64 qc = (u64)(u32)rintf(c * (16.0f/1440.0f));
        u64 qh = (u64)(u32)rintf(h * 16.0f);
        u64 qs = (u64)(u32)rintf((cs + 1.0f) * 16.0f);
        u64 qr = (u64)(u32)rintf(r * 16.0f);
        u64 qe = (u64)(u32)rintf(e * 16.0f);
        packed[i] = qc | (qh << 11) | (qs << 22) | (qr << 34) | (qe << 45) | (1ULL << 56);

        ah = fabsf(h); ac = fabsf(cs); ar = fabsf(r); ae = fabsf(e);
        sc = c; sh = h; sr = r;
    }
    ah = waveReduceMax(ah); ac = waveReduceMax(ac);
    ar = waveReduceMax(ar); ae = waveReduceMax(ae);
    sc = waveReduceSum(sc); sh = waveReduceSum(sh); sr = waveReduceSum(sr);

    __shared__ float red[4][7];
    int wid = threadIdx.x >> 6;
    if ((threadIdx.x & 63) == 0) {
        red[wid][0] = ah; red[wid][1] = ac; red[wid][2] = ar; red[wid][3] = ae;
        red[wid][4] = sc; red[wid][5] = sh; red[wid][6] = sr;
    }
    __syncthreads();
    if (threadIdx.x == 0) {
        float* p = partials + (size_t)blockIdx.x * 8;
        p[0] = fmaxf(fmaxf(red[0][0], red[1][0]), fmaxf(red[2][0], red[3][0]));
        p[1] = fmaxf(fmaxf(red[0][1], red[1][1]), fmaxf(red[2][1], red[3][1]));
        p[2] = fmaxf(fmaxf(red[0][2], red[1][2]), fmaxf(red[2][2], red[3][2]));
        p[3] = fmaxf(fmaxf(red[0][3], red[1][3]), fmaxf(red[2][3], red[3][3]));
        p[4] = red[0][4] + red[1][4] + red[2][4] + red[3][4];
        p[5] = red[0][5] + red[1][5] + red[2][5] + red[3][5];
        p[6] = red[0][6] + red[1][6] + red[2][6] + red[3][6];
    }
}

__global__ __launch_bounds__(256) void k1b_reduce(
    const float* __restrict__ partials, float* __restrict__ accum, int nblocks)
{
    float mh = 0.f, mc = 0.f, mr = 0.f, me = 0.f, sc = 0.f, sh = 0.f, sr = 0.f;
    for (int b = threadIdx.x; b < nblocks; b += 256) {
        const float* p = partials + (size_t)b * 8;
        mh = fmaxf(mh, p[0]); mc = fmaxf(mc, p[1]);
        mr = fmaxf(mr, p[2]); me = fmaxf(me, p[3]);
        sc += p[4]; sh += p[5]; sr += p[6];
    }
    mh = waveReduceMax(mh); mc = waveReduceMax(mc);
    mr = waveReduceMax(mr); me = waveReduceMax(me);
    sc = waveReduceSum(sc); sh = waveReduceSum(sh); sr = waveReduceSum(sr);
    __shared__ float red[4][7];
    int wid = threadIdx.x >> 6;
    if ((threadIdx.x & 63) == 0) {
        red[wid][0] = mh; red[wid][1] = mc; red[wid][2] = mr; red[wid][3] = me;
        red[wid][4] = sc; red[wid][5] = sh; red[wid][6] = sr;
    }
    __syncthreads();
    if (threadIdx.x == 0) {
        accum[0] = fmaxf(fmaxf(red[0][0], red[1][0]), fmaxf(red[2][0], red[3][0]));
        accum[1] = fmaxf(fmaxf(red[0][1], red[1][1]), fmaxf(red[2][1], red[3][1]));
        accum[2] = fmaxf(fmaxf(red[0][2], red[1][2]), fmaxf(red[2][2], red[3][2]));
        accum[3] = fmaxf(fmaxf(red[0][3], red[1][3]), fmaxf(red[2][3], red[3][3]));
        accum[4] = red[0][4] + red[1][4] + red[2][4] + red[3][4];
        accum[5] = red[0][5] + red[1][5] + red[2][5] + red[3][5];
        accum[6] = red[0][6] + red[1][6] + red[2][6] + red[3][6];
    }
}

// ---- Phase A: bucket-scatter ---------------------------------------------
// records[b*cap + slot] = (src << 12) | (dst & 4095),  bucket b = dst >> 12
__global__ __launch_bounds__(256) void k2a_scatter(
    const int* __restrict__ src, const int* __restrict__ dst,
    u32* __restrict__ records, u32* __restrict__ bucketPos,
    int E, int nb, int cap, int chunk)
{
    __shared__ u32 hist[128];
    __shared__ u32 base[128];
    int b0 = blockIdx.x * chunk;
    int b1 = min(b0 + chunk, E);
    for (int i = threadIdx.x; i < nb; i += 256) hist[i] = 0;
    __syncthreads();
    for (int e = b0 + threadIdx.x; e < b1; e += 256)
        atomicAdd(&hist[dst[e] >> 12], 1u);
    __syncthreads();
    for (int i = threadIdx.x; i < nb; i += 256) {
        base[i] = atomicAdd(&bucketPos[i], hist[i]);
        hist[i] = 0;
    }
    __syncthreads();
    for (int e = b0 + threadIdx.x; e < b1; e += 256) {
        int d = dst[e];
        int b = d >> 12;
        u32 off = base[b] + atomicAdd(&hist[b], 1u);
        if (off < (u32)cap)
            records[(size_t)b * cap + off] = ((u32)src[e] << 12) | (u32)(d & 4095);
    }
}

// ---- Phase B: LDS accumulate + replica flush -----------------------------
__global__ __launch_bounds__(256) void k2b_accum(
    const u32* __restrict__ records, const u32* __restrict__ bucketPos,
    const u64* __restrict__ packed, u64* __restrict__ S2rep,
    int n, int cap, int nsl)
{
    __shared__ u64 acc[4096];   // 32 KB
    int bucket = blockIdx.x / nsl;
    int slice  = blockIdx.x % nsl;
    int nodeBase = bucket << 12;
    int nNodes = min(4096, n - nodeBase);
    for (int i = threadIdx.x; i < 4096; i += 256) acc[i] = 0;
    __syncthreads();
    u32 cnt = bucketPos[bucket];
    if (cnt > (u32)cap) cnt = (u32)cap;
    u32 lo = (u32)(((u64)cnt * (u32)slice) / (u32)nsl);
    u32 hi = (u32)(((u64)cnt * (u32)(slice + 1)) / (u32)nsl);
    const u32* rec = records + (size_t)bucket * cap;
    for (u32 r = lo + threadIdx.x; r < hi; r += 256) {
        u32 v = rec[r];
        atomicAdd(&acc[v & 4095u], packed[v >> 12]);
    }
    __syncthreads();
    u64* dstp = S2rep + (size_t)slice * n + nodeBase;
    for (int i = threadIdx.x; i < nNodes; i += 256) dstp[i] = acc[i];
}

__global__ __launch_bounds__(256) void k3_mlp(
    const float4* __restrict__ featA, const float* __restrict__ ct,
    const u64* __restrict__ S2rep, int nsl, const int* __restrict__ nid,
    const int* __restrict__ currp,
    const float* __restrict__ aW2, const float* __restrict__ ab2,
    const float* __restrict__ aW3, const float* __restrict__ ab3,
    const float* __restrict__ aW4, const float* __restrict__ ab4,
    const float* __restrict__ accum, float* __restrict__ partials2,
    float* __restrict__ out, int n)
{
    __shared__ float w3s[128 * 64];   // 32 KB
    for (int idx = threadIdx.x; idx < 128 * 64; idx += 256)
        w3s[idx] = aW3[idx];
    __syncthreads();

    int i0 = blockIdx.x * blockDim.x + threadIdx.x;
    int i = i0 < n ? i0 : n - 1;           // clamp: no divergence in compute
    bool valid = i0 < n;

    float inv_mh = 1.0f / fmaxf(accum[0], 1e-12f);
    float inv_mc = 1.0f / fmaxf(accum[1], 1e-12f);
    float inv_mr = 1.0f / fmaxf(accum[2], 1e-12f);
    float inv_me = 1.0f / fmaxf(accum[3], 1e-12f);
    int curr = currp[0];

    float4 f = featA[i];
    float c = ct[i];
    u64 P = 0;
    for (int s = 0; s < nsl; ++s) P += S2rep[(size_t)s * n + i];
    u32 qct = (u32)(P         & 0x7FFULL);
    u32 qh  = (u32)((P >> 11) & 0x7FFULL);
    u32 qcs = (u32)((P >> 22) & 0xFFFULL);
    u32 qr  = (u32)((P >> 34) & 0x7FFULL);
    u32 qe  = (u32)((P >> 45) & 0x7FFULL);
    u32 deg = (u32)(P >> 56);
    float icd = deg ? 1.0f / (16.0f * (float)deg) : 0.f;
    float x0 = (float)qct * icd;                                   // mean ct/1440
    float x1 = (float)qh  * icd * inv_mh;
    float x2 = deg ? ((float)qcs * icd - 1.0f) * inv_mc : 0.f;
    float x3 = (float)qr  * icd * inv_mr;
    float x4 = (float)qe  * icd * inv_me;
    float f0 = c * (1.0f/1440.0f);
    float f1 = f.x * inv_mh, f2 = f.y * inv_mc, f3 = f.z * inv_mr, f4 = f.w * inv_me;
    float g0 = 0.5f*(f0+x0), g1 = 0.5f*(f1+x1), g2 = 0.5f*(f2+x2),
          g3 = 0.5f*(f3+x3), g4 = 0.5f*(f4+x4);

    float acc[64];
#pragma unroll
    for (int k = 0; k < 64; ++k) acc[k] = ab3[k];

    for (int j = 0; j < 128; j += 4) {
        float hv[4];
#pragma unroll
        for (int jj = 0; jj < 4; ++jj) {
            float t = ab2[j + jj];
            t = fmaf(g0, aW2[j + jj],       t);
            t = fmaf(g1, aW2[128 + j + jj], t);
            t = fmaf(g2, aW2[256 + j + jj], t);
            t = fmaf(g3, aW2[384 + j + jj], t);
            t = fmaf(g4, aW2[512 + j + jj], t);
            hv[jj] = sigf(t);
        }
        const float4* r0 = (const float4*)&w3s[(j + 0) * 64];
        const float4* r1 = (const float4*)&w3s[(j + 1) * 64];
        const float4* r2 = (const float4*)&w3s[(j + 2) * 64];
        const float4* r3 = (const float4*)&w3s[(j + 3) * 64];
#pragma unroll
        for (int k4 = 0; k4 < 16; ++k4) {
            float4 a = r0[k4], b = r1[k4], cc = r2[k4], d = r3[k4];
            acc[4*k4+0] = fmaf(hv[0], a.x, fmaf(hv[1], b.x, fmaf(hv[2], cc.x, fmaf(hv[3], d.x, acc[4*k4+0]))));
            acc[4*k4+1] = fmaf(hv[0], a.y, fmaf(hv[1], b.y, fmaf(hv[2], cc.y, fmaf(hv[3], d.y, acc[4*k4+1]))));
            acc[4*k4+2] = fmaf(hv[0], a.z, fmaf(hv[1], b.z, fmaf(hv[2], cc.z, fmaf(hv[3], d.z, acc[4*k4+2]))));
            acc[4*k4+3] = fmaf(hv[0], a.w, fmaf(hv[1], b.w, fmaf(hv[2], cc.w, fmaf(hv[3], d.w, acc[4*k4+3]))));
        }
    }

    float p = ab4[0];
#pragma unroll
    for (int k = 0; k < 64; ++k) p = fmaf(sigf(acc[k]), aW4[k], p);

    float ev = (valid && nid[i] != curr) ? __expf(p) : 0.f;
    if (valid) out[i0] = ev;
    float r0s = valid ? x0 : 0.f;
    float r1s = valid ? x1 : 0.f;
    float r3s = valid ? x3 : 0.f;

    ev  = waveReduceSum(ev);
    r0s = waveReduceSum(r0s);
    r1s = waveReduceSum(r1s);
    r3s = waveReduceSum(r3s);

    __shared__ float red[4][4];
    int wid = threadIdx.x >> 6;
    if ((threadIdx.x & 63) == 0) {
        red[wid][0] = ev; red[wid][1] = r0s; red[wid][2] = r1s; red[wid][3] = r3s;
    }
    __syncthreads();
    if (threadIdx.x == 0) {
        float* p2 = partials2 + (size_t)blockIdx.x * 4;
        p2[0] = red[0][0] + red[1][0] + red[2][0] + red[3][0];
        p2[1] = red[0][1] + red[1][1] + red[2][1] + red[3][1];
        p2[2] = red[0][2] + red[1][2] + red[2][2] + red[3][2];
        p2[3] = red[0][3] + red[1][3] + red[2][3] + red[3][3];
    }
}

__global__ __launch_bounds__(256) void k3b_reduce(
    const float* __restrict__ partials2, float* __restrict__ accum, int nblocks)
{
    float s0 = 0.f, s1 = 0.f, s2 = 0.f, s3 = 0.f;
    for (int b = threadIdx.x; b < nblocks; b += 256) {
        const float* p = partials2 + (size_t)b * 4;
        s0 += p[0]; s1 += p[1]; s2 += p[2]; s3 += p[3];
    }
    s0 = waveReduceSum(s0); s1 = waveReduceSum(s1);
    s2 = waveReduceSum(s2); s3 = waveReduceSum(s3);
    __shared__ float red[4][4];
    int wid = threadIdx.x >> 6;
    if ((threadIdx.x & 63) == 0) {
        red[wid][0] = s0; red[wid][1] = s1; red[wid][2] = s2; red[wid][3] = s3;
    }
    __syncthreads();
    if (threadIdx.x == 0) {
        accum[7]  = red[0][0] + red[1][0] + red[2][0] + red[3][0];
        accum[8]  = red[0][1] + red[1][1] + red[2][1] + red[3][1];
        accum[9]  = red[0][2] + red[1][2] + red[2][2] + red[3][2];
        accum[10] = red[0][3] + red[1][3] + red[2][3] + red[3][3];
    }
}

__global__ void k4_critic(const float* __restrict__ accum,
                          const float* __restrict__ cW2, const float* __restrict__ cb2,
                          const float* __restrict__ cW3, const float* __restrict__ cb3,
                          const float* __restrict__ cW4, const float* __restrict__ cb4,
                          float* __restrict__ out, int n)
{
    __shared__ float v1[128];
    __shared__ float v2[64];
    int t = threadIdx.x;
    float invN = 1.0f / (float)n;
    float inv_mh = 1.0f / fmaxf(accum[0], 1e-12f);
    float inv_mr = 1.0f / fmaxf(accum[2], 1e-12f);
    float cx0 = accum[4] * invN * (1.0f / 1440.0f);
    float cx1 = accum[5] * invN * inv_mh;
    float cx2 = accum[6] * invN * inv_mr;
    float cx3 = accum[8] * invN;
    float cx4 = accum[9] * invN;
    float cx5 = accum[10] * invN;
    if (t < 128) {
        float a = cb2[t];
        a = fmaf(cx0, cW2[t],       a);
        a = fmaf(cx1, cW2[128 + t], a);
        a = fmaf(cx2, cW2[256 + t], a);
        a = fmaf(cx3, cW2[384 + t], a);
        a = fmaf(cx4, cW2[512 + t], a);
        a = fmaf(cx5, cW2[640 + t], a);
        v1[t] = sigf(a);
    }
    __syncthreads();
    if (t < 64) {
        float a = cb3[t];
        for (int j = 0; j < 128; ++j) a = fmaf(v1[j], cW3[j * 64 + t], a);
        v2[t] = sigf(a);
    }
    __syncthreads();
    if (t == 0) {
        float a = cb4[0];
        for (int k = 0; k < 64; ++k) a = fmaf(v2[k], cW4[k], a);
        out[n] = a;  // value
    }
}

__global__ void k5_scale(float* __restrict__ out, const float* __restrict__ accum, int n)
{
    int i = blockIdx.x * blockDim.x + threadIdx.x;
    float inv = 1.0f / accum[7];
    if (i < n) out[i] *= inv;
}

extern "C" void kernel_launch(void* const* d_in, const int* in_sizes, int n_in,
                              void* d_out, int out_size, void* d_ws, size_t ws_size,
                              hipStream_t stream)
{
    const float* hop = (const float*)d_in[0];
    const float* rd  = (const float*)d_in[1];
    const float* ett = (const float*)d_in[2];
    const float* ct  = (const float*)d_in[3];
    const float* c2n = (const float*)d_in[4];
    const float* c2t = (const float*)d_in[5];
    const int*   nid = (const int*)d_in[6];
    const int*   src = (const int*)d_in[7];
    const int*   dst = (const int*)d_in[8];
    const int*   cur = (const int*)d_in[9];
    const float* aW2 = (const float*)d_in[10];
    const float* ab2 = (const float*)d_in[11];
    const float* aW3 = (const float*)d_in[12];
    const float* ab3 = (const float*)d_in[13];
    const float* aW4 = (const float*)d_in[14];
    const float* ab4 = (const float*)d_in[15];
    const float* cW2 = (const float*)d_in[16];
    const float* cb2 = (const float*)d_in[17];
    const float* cW3 = (const float*)d_in[18];
    const float* cb3 = (const float*)d_in[19];
    const float* cW4 = (const float*)d_in[20];
    const float* cb4 = (const float*)d_in[21];

    int n = in_sizes[0];
    int E = in_sizes[7];
    float* out = (float*)d_out;

    const int NSL = 4;
    int nb  = (n + 4095) >> 12;                       // buckets of 4096 nodes
    int cap = E / (nb > 0 ? nb : 1) + 8192;           // >25 sigma slack
    int nbk = (n + 255) / 256;

    char* ws = (char*)d_ws;
    float4* featA  = (float4*)ws;                     // 16n
    u64*    packed = (u64*)(ws + (size_t)16 * n);     // 8n
    u64*    S2rep  = (u64*)(ws + (size_t)24 * n);     // 8n * NSL = 32n

    size_t tail_bucket = (size_t)56 * n;
    size_t tail_fb     = (size_t)32 * n;
    size_t tailsz = 1024 + (size_t)48 * nbk;          // accum+bucketPos+partials+partials2
    size_t needed = tail_bucket + tailsz + (size_t)nb * cap * 4;
    bool bucketPath = (ws_size >= needed) && (nb <= 128);

    char* base = ws + (bucketPath ? tail_bucket : tail_fb);
    float* accum     = (float*)base;                          // 256 B
    u32*   bucketPos = (u32*)(base + 256);                    // up to 512 B
    float* partials  = (float*)(base + 1024);                 // 32*nbk B
    float* partials2 = (float*)(base + 1024 + (size_t)32 * nbk); // 16*nbk B
    u32*   records   = (u32*)(base + tailsz);

    if (bucketPath) {
        hipMemsetAsync(bucketPos, 0, 512, stream);
        k1_prep<<<nbk, 256, 0, stream>>>(hop, rd, ett, ct, c2n, c2t, featA, packed, partials, n);
        k1b_reduce<<<1, 256, 0, stream>>>(partials, accum, nbk);
        int chunk = (E + 1023) / 1024;
        k2a_scatter<<<1024, 256, 0, stream>>>(src, dst, records, bucketPos, E, nb, cap, chunk);
        k2b_accum<<<nb * NSL, 256, 0, stream>>>(records, bucketPos, packed, S2rep, n, cap, NSL);
        k3_mlp<<<nbk, 256, 0, stream>>>(featA, ct, S2rep, NSL, nid, cur,
                                        aW2, ab2, aW3, ab3, aW4, ab4, accum, partials2, out, n);
        k3b_reduce<<<1, 256, 0, stream>>>(partials2, accum, nbk);
    } else {
        // fallback: one global u64 atomic per edge into S2 (= S2rep slice 0)
        u64* S2f = (u64*)(ws + (size_t)24 * n);
        hipMemsetAsync(S2f, 0, (size_t)8 * n, stream);
        k1_prep<<<nbk, 256, 0, stream>>>(hop, rd, ett, ct, c2n, c2t, featA, packed, partials, n);
        k1b_reduce<<<1, 256, 0, stream>>>(partials, accum, nbk);
        // reuse k2b grid-stride atomic path via a tiny lambda-less kernel:
        // (declared below as k2_atomic)
        extern __global__ void k2_atomic(const int*, const int*, const u64*, u64*, int);
        k2_atomic<<<4096, 256, 0, stream>>>(src, dst, packed, S2f, E);
        k3_mlp<<<nbk, 256, 0, stream>>>(featA, ct, S2f, 1, nid, cur,
                                        aW2, ab2, aW3, ab3, aW4, ab4, accum, partials2, out, n);
        k3b_reduce<<<1, 256, 0, stream>>>(partials2, accum, nbk);
    }
    k4_critic<<<1, 128, 0, stream>>>(accum, cW2, cb2, cW3, cb3, cW4, cb4, out, n);
    k5_scale<<<nbk, 256, 0, stream>>>(out, accum, n);
}

// fallback kernel definition (after kernel_launch for clarity)
__global__ void k2_atomic(const int* __restrict__ src, const int* __restrict__ dst,
                          const u64* __restrict__ packed, u64* __restrict__ S2, int E)
{
    int stride = gridDim.x * blockDim.x;
    for (int e = blockIdx.x * blockDim.x + threadIdx.x; e < E; e += stride) {
        atomicAdd(S2 + dst[e], packed[src[e]]);
    }
}